// Round 5
// baseline (138.502 us; speedup 1.0000x reference)
//
#include <hip/hip_runtime.h>

#define N_ROWS 8192LL
#define N_COLS 10000LL
#define GRID_BLKS 2048
#define BLOCK 256

// out[0] = loss_m.sum()/n, out[1] = loss_inter.sum()/n
// S_all  = sum over ALL entries of max(x+25, 0)
// per-target: plus = max(x_t+25,0) (wrongly counted in S_all), hinge = max(50-x_t,0)
// out1 = (S_all - sum plus)/n ; out0 = out1 + (sum hinge)/n
//
// ws layout: float2 partials[GRID_BLKS] | unsigned counter (memset to 0 per call)

typedef float f4 __attribute__((ext_vector_type(4)));   // native vector: nontemporal-loadable

union F2U { float2 f; unsigned long long u; };

__global__ void __launch_bounds__(BLOCK) hinge_onepass(const f4* __restrict__ in4,
                                                       const float* __restrict__ in,
                                                       const int* __restrict__ tgt,
                                                       float2* __restrict__ ws,
                                                       unsigned* __restrict__ counter,
                                                       float* __restrict__ out) {
    const long long n4 = N_ROWS * N_COLS / 4;          // 20,480,000
    const long long stride = (long long)GRID_BLKS * BLOCK;
    const long long gid = (long long)blockIdx.x * BLOCK + threadIdx.x;

    float acc = 0.0f;
    for (long long i = gid; i < n4; i += stride) {
        f4 v = __builtin_nontemporal_load(&in4[i]);   // streaming: no reuse, skip cache
        acc += fmaxf(v.x + 25.0f, 0.0f) + fmaxf(v.y + 25.0f, 0.0f)
             + fmaxf(v.z + 25.0f, 0.0f) + fmaxf(v.w + 25.0f, 0.0f);
    }

    // fold the 8192 target-column corrections into the first 8192 threads
    float d0 = acc, d1 = acc;
    if (gid < N_ROWS) {
        int t = tgt[gid];
        float x = in[gid * N_COLS + (long long)t];
        float plus  = fmaxf(x + 25.0f, 0.0f);
        float hinge = fmaxf(50.0f - x, 0.0f);
        d0 += hinge - plus;
        d1 -= plus;
    }

    #pragma unroll
    for (int off = 32; off > 0; off >>= 1) {
        d0 += __shfl_down(d0, off, 64);
        d1 += __shfl_down(d1, off, 64);
    }
    __shared__ float s0[4], s1[4];
    __shared__ bool amLast;
    const int lane = threadIdx.x & 63;
    const int wid  = threadIdx.x >> 6;
    if (lane == 0) { s0[wid] = d0; s1[wid] = d1; }
    __syncthreads();

    if (threadIdx.x == 0) {
        F2U p;
        p.f = make_float2(s0[0] + s0[1] + s0[2] + s0[3],
                          s1[0] + s1[1] + s1[2] + s1[3]);
        // device-scope release store of this block's partial, then signal
        __hip_atomic_store((unsigned long long*)&ws[blockIdx.x], p.u,
                           __ATOMIC_RELEASE, __HIP_MEMORY_SCOPE_AGENT);
        unsigned prev = __hip_atomic_fetch_add(counter, 1u,
                           __ATOMIC_ACQ_REL, __HIP_MEMORY_SCOPE_AGENT);
        amLast = (prev == GRID_BLKS - 1);
    }
    __syncthreads();

    if (amLast) {   // exactly one block: reduce all partials in fixed order
        float t0 = 0.0f, t1 = 0.0f;
        for (int k = threadIdx.x; k < GRID_BLKS; k += BLOCK) {
            F2U p;
            p.u = __hip_atomic_load((const unsigned long long*)&ws[k],
                                    __ATOMIC_RELAXED, __HIP_MEMORY_SCOPE_AGENT);
            t0 += p.f.x; t1 += p.f.y;
        }
        #pragma unroll
        for (int off = 32; off > 0; off >>= 1) {
            t0 += __shfl_down(t0, off, 64);
            t1 += __shfl_down(t1, off, 64);
        }
        if (lane == 0) { s0[wid] = t0; s1[wid] = t1; }
        __syncthreads();
        if (threadIdx.x == 0) {
            const float inv_n = 1.0f / (float)N_ROWS;
            out[0] = (s0[0] + s0[1] + s0[2] + s0[3]) * inv_n;
            out[1] = (s1[0] + s1[1] + s1[2] + s1[3]) * inv_n;
        }
    }
}

extern "C" void kernel_launch(void* const* d_in, const int* in_sizes, int n_in,
                              void* d_out, int out_size, void* d_ws, size_t ws_size,
                              hipStream_t stream) {
    const float* inputs = (const float*)d_in[0];
    const int* targets = (const int*)d_in[1];
    float* out = (float*)d_out;
    float2* ws = (float2*)d_ws;                                       // 16 KB partials
    unsigned* counter = (unsigned*)((char*)d_ws + GRID_BLKS * sizeof(float2));

    (void)hipMemsetAsync(counter, 0, sizeof(unsigned), stream);   // ws is poisoned once; re-zero per call

    hinge_onepass<<<GRID_BLKS, BLOCK, 0, stream>>>((const f4*)inputs, inputs,
                                                   targets, ws, counter, out);
}

// Round 6
// 62.868 us; speedup vs baseline: 2.2031x; 2.2031x over previous
//
#include <hip/hip_runtime.h>

#define N_ROWS 8192LL
#define N_COLS 10000LL
#define GRID_BLKS 2048
#define BLOCK 256

// out[0] = loss_m.sum()/n, out[1] = loss_inter.sum()/n
// S_all  = sum over ALL entries of max(x+25, 0)
// per-target: plus = max(x_t+25,0) (wrongly counted in S_all), hinge = max(50-x_t,0)
// out1 = (S_all - sum plus)/n ; out0 = out1 + (sum hinge)/n

__global__ void __launch_bounds__(BLOCK) hinge_partials(const float4* __restrict__ in4,
                                                        const float* __restrict__ in,
                                                        const int* __restrict__ tgt,
                                                        float2* __restrict__ ws) {
    const long long n4 = N_ROWS * N_COLS / 4;          // 20,480,000
    const long long stride = (long long)GRID_BLKS * BLOCK;
    const long long gid = (long long)blockIdx.x * BLOCK + threadIdx.x;

    // 2x unroll, independent accumulators -> 2 outstanding dwordx4 loads/thread
    float accA = 0.0f, accB = 0.0f;
    long long i = gid;
    for (; i + stride < n4; i += 2 * stride) {
        float4 a = in4[i];
        float4 b = in4[i + stride];
        accA += fmaxf(a.x + 25.0f, 0.0f) + fmaxf(a.y + 25.0f, 0.0f)
              + fmaxf(a.z + 25.0f, 0.0f) + fmaxf(a.w + 25.0f, 0.0f);
        accB += fmaxf(b.x + 25.0f, 0.0f) + fmaxf(b.y + 25.0f, 0.0f)
              + fmaxf(b.z + 25.0f, 0.0f) + fmaxf(b.w + 25.0f, 0.0f);
    }
    if (i < n4) {
        float4 a = in4[i];
        accA += fmaxf(a.x + 25.0f, 0.0f) + fmaxf(a.y + 25.0f, 0.0f)
              + fmaxf(a.z + 25.0f, 0.0f) + fmaxf(a.w + 25.0f, 0.0f);
    }
    float acc = accA + accB;

    // fold the 8192 target-column corrections into the first 8192 threads
    float d0 = acc, d1 = acc;
    if (gid < N_ROWS) {
        int t = tgt[gid];
        float x = in[gid * N_COLS + (long long)t];
        float plus  = fmaxf(x + 25.0f, 0.0f);
        float hinge = fmaxf(50.0f - x, 0.0f);
        d0 += hinge - plus;
        d1 -= plus;
    }

    #pragma unroll
    for (int off = 32; off > 0; off >>= 1) {
        d0 += __shfl_down(d0, off, 64);
        d1 += __shfl_down(d1, off, 64);
    }
    __shared__ float s0[4], s1[4];
    const int lane = threadIdx.x & 63;
    const int wid  = threadIdx.x >> 6;
    if (lane == 0) { s0[wid] = d0; s1[wid] = d1; }
    __syncthreads();
    if (threadIdx.x == 0) {
        // contention-free per-block partial store (distinct cachelines across blocks)
        ws[blockIdx.x] = make_float2(s0[0] + s0[1] + s0[2] + s0[3],
                                     s1[0] + s1[1] + s1[2] + s1[3]);
    }
}

__global__ void __launch_bounds__(1024) hinge_reduce(const float2* __restrict__ ws,
                                                     float* __restrict__ out) {
    // 2048 float2 partials; 1024 threads, 2 each
    float2 a = ws[threadIdx.x];
    float2 b = ws[threadIdx.x + 1024];
    float d0 = a.x + b.x;
    float d1 = a.y + b.y;
    #pragma unroll
    for (int off = 32; off > 0; off >>= 1) {
        d0 += __shfl_down(d0, off, 64);
        d1 += __shfl_down(d1, off, 64);
    }
    __shared__ float s0[16], s1[16];
    const int lane = threadIdx.x & 63;
    const int wid  = threadIdx.x >> 6;
    if (lane == 0) { s0[wid] = d0; s1[wid] = d1; }
    __syncthreads();
    if (threadIdx.x == 0) {
        float t0 = 0.0f, t1 = 0.0f;
        #pragma unroll
        for (int k = 0; k < 16; ++k) { t0 += s0[k]; t1 += s1[k]; }
        const float inv_n = 1.0f / (float)N_ROWS;
        out[0] = t0 * inv_n;   // plain overwrite — no memset node needed
        out[1] = t1 * inv_n;
    }
}

extern "C" void kernel_launch(void* const* d_in, const int* in_sizes, int n_in,
                              void* d_out, int out_size, void* d_ws, size_t ws_size,
                              hipStream_t stream) {
    const float* inputs = (const float*)d_in[0];
    const int* targets = (const int*)d_in[1];
    float* out = (float*)d_out;
    float2* ws = (float2*)d_ws;   // needs 2048 * 8 = 16 KB scratch

    hinge_partials<<<GRID_BLKS, BLOCK, 0, stream>>>((const float4*)inputs, inputs, targets, ws);
    hinge_reduce<<<1, 1024, 0, stream>>>(ws, out);
}

// Round 7
// 59.114 us; speedup vs baseline: 2.3430x; 1.0635x over previous
//
#include <hip/hip_runtime.h>

#define N_ROWS 8192LL
#define N_COLS 10000LL
#define GRID_BLKS 2048
#define BLOCK 256
#define CHUNK 10000   // float4s per block: 8192*10000/4 / 2048 = 10000 exactly

// out[0] = loss_m.sum()/n, out[1] = loss_inter.sum()/n
// S_all  = sum over ALL entries of max(x+25, 0)
// per-target: plus = max(x_t+25,0) (wrongly counted in S_all), hinge = max(50-x_t,0)
// out1 = (S_all - sum plus)/n ; out0 = out1 + (sum hinge)/n

__global__ void __launch_bounds__(BLOCK) hinge_partials(const float4* __restrict__ in4,
                                                        const float* __restrict__ in,
                                                        const int* __restrict__ tgt,
                                                        float2* __restrict__ ws) {
    // block-contiguous chunk: 160 KB per block, dual in-flight loads 4 KB apart
    const long long base = (long long)blockIdx.x * CHUNK;
    float accA = 0.0f, accB = 0.0f;
    int j = threadIdx.x;
    for (; j + BLOCK < CHUNK; j += 2 * BLOCK) {
        float4 a = in4[base + j];
        float4 b = in4[base + j + BLOCK];
        accA += fmaxf(a.x + 25.0f, 0.0f) + fmaxf(a.y + 25.0f, 0.0f)
              + fmaxf(a.z + 25.0f, 0.0f) + fmaxf(a.w + 25.0f, 0.0f);
        accB += fmaxf(b.x + 25.0f, 0.0f) + fmaxf(b.y + 25.0f, 0.0f)
              + fmaxf(b.z + 25.0f, 0.0f) + fmaxf(b.w + 25.0f, 0.0f);
    }
    if (j < CHUNK) {
        float4 a = in4[base + j];
        accA += fmaxf(a.x + 25.0f, 0.0f) + fmaxf(a.y + 25.0f, 0.0f)
              + fmaxf(a.z + 25.0f, 0.0f) + fmaxf(a.w + 25.0f, 0.0f);
    }
    float acc = accA + accB;

    // fold the 8192 target-column corrections into the first 8192 threads
    const long long gid = (long long)blockIdx.x * BLOCK + threadIdx.x;
    float d0 = acc, d1 = acc;
    if (gid < N_ROWS) {
        int t = tgt[gid];
        float x = in[gid * N_COLS + (long long)t];
        float plus  = fmaxf(x + 25.0f, 0.0f);
        float hinge = fmaxf(50.0f - x, 0.0f);
        d0 += hinge - plus;
        d1 -= plus;
    }

    #pragma unroll
    for (int off = 32; off > 0; off >>= 1) {
        d0 += __shfl_down(d0, off, 64);
        d1 += __shfl_down(d1, off, 64);
    }
    __shared__ float s0[4], s1[4];
    const int lane = threadIdx.x & 63;
    const int wid  = threadIdx.x >> 6;
    if (lane == 0) { s0[wid] = d0; s1[wid] = d1; }
    __syncthreads();
    if (threadIdx.x == 0) {
        // contention-free per-block partial store (distinct cachelines across blocks)
        ws[blockIdx.x] = make_float2(s0[0] + s0[1] + s0[2] + s0[3],
                                     s1[0] + s1[1] + s1[2] + s1[3]);
    }
}

__global__ void __launch_bounds__(1024) hinge_reduce(const float2* __restrict__ ws,
                                                     float* __restrict__ out) {
    // 2048 float2 partials; 1024 threads, 2 each
    float2 a = ws[threadIdx.x];
    float2 b = ws[threadIdx.x + 1024];
    float d0 = a.x + b.x;
    float d1 = a.y + b.y;
    #pragma unroll
    for (int off = 32; off > 0; off >>= 1) {
        d0 += __shfl_down(d0, off, 64);
        d1 += __shfl_down(d1, off, 64);
    }
    __shared__ float s0[16], s1[16];
    const int lane = threadIdx.x & 63;
    const int wid  = threadIdx.x >> 6;
    if (lane == 0) { s0[wid] = d0; s1[wid] = d1; }
    __syncthreads();
    if (threadIdx.x == 0) {
        float t0 = 0.0f, t1 = 0.0f;
        #pragma unroll
        for (int k = 0; k < 16; ++k) { t0 += s0[k]; t1 += s1[k]; }
        const float inv_n = 1.0f / (float)N_ROWS;
        out[0] = t0 * inv_n;   // plain overwrite — no memset node needed
        out[1] = t1 * inv_n;
    }
}

extern "C" void kernel_launch(void* const* d_in, const int* in_sizes, int n_in,
                              void* d_out, int out_size, void* d_ws, size_t ws_size,
                              hipStream_t stream) {
    const float* inputs = (const float*)d_in[0];
    const int* targets = (const int*)d_in[1];
    float* out = (float*)d_out;
    float2* ws = (float2*)d_ws;   // needs 2048 * 8 = 16 KB scratch

    hinge_partials<<<GRID_BLKS, BLOCK, 0, stream>>>((const float4*)inputs, inputs, targets, ws);
    hinge_reduce<<<1, 1024, 0, stream>>>(ws, out);
}

// Round 8
// 56.356 us; speedup vs baseline: 2.4576x; 1.0489x over previous
//
#include <hip/hip_runtime.h>

#define N_ROWS 8192LL
#define N_COLS 10000LL
#define GRID_BLKS 2048

// out[0] = loss_m.sum()/n, out[1] = loss_inter.sum()/n
// S_all  = sum over ALL entries of max(x+25, 0)
// per-target: plus = max(x_t+25,0) (wrongly counted in S_all), hinge = max(50-x_t,0)
// out1 = (S_all - sum plus)/n ; out0 = out1 + (sum hinge)/n
//
// R3 structure (best measured: 56.5 µs):
//  - grid-stride sweep, one dwordx4/thread/iter (1 KB per wave per instr)
//  - contention-free float2 partial store per block (no atomics -> no serialization tail)
//  - tiny second kernel reduces 2048 partials and overwrites out (no memset node)

__global__ void __launch_bounds__(256) hinge_partials(const float4* __restrict__ in4,
                                                      const float* __restrict__ in,
                                                      const int* __restrict__ tgt,
                                                      float2* __restrict__ ws) {
    const long long n4 = N_ROWS * N_COLS / 4;          // 20,480,000
    const long long stride = (long long)GRID_BLKS * 256;
    const long long gid = (long long)blockIdx.x * blockDim.x + threadIdx.x;

    float acc = 0.0f;
    for (long long i = gid; i < n4; i += stride) {
        float4 v = in4[i];
        acc += fmaxf(v.x + 25.0f, 0.0f) + fmaxf(v.y + 25.0f, 0.0f)
             + fmaxf(v.z + 25.0f, 0.0f) + fmaxf(v.w + 25.0f, 0.0f);
    }

    // fold the 8192 target-column corrections into the first 8192 threads
    float d0 = acc, d1 = acc;
    if (gid < N_ROWS) {
        int t = tgt[gid];
        float x = in[gid * N_COLS + (long long)t];
        float plus  = fmaxf(x + 25.0f, 0.0f);
        float hinge = fmaxf(50.0f - x, 0.0f);
        d0 += hinge - plus;
        d1 -= plus;
    }

    #pragma unroll
    for (int off = 32; off > 0; off >>= 1) {
        d0 += __shfl_down(d0, off, 64);
        d1 += __shfl_down(d1, off, 64);
    }
    __shared__ float s0[4], s1[4];
    const int lane = threadIdx.x & 63;
    const int wid  = threadIdx.x >> 6;
    if (lane == 0) { s0[wid] = d0; s1[wid] = d1; }
    __syncthreads();
    if (threadIdx.x == 0) {
        // contention-free per-block partial store
        ws[blockIdx.x] = make_float2(s0[0] + s0[1] + s0[2] + s0[3],
                                     s1[0] + s1[1] + s1[2] + s1[3]);
    }
}

__global__ void __launch_bounds__(1024) hinge_reduce(const float2* __restrict__ ws,
                                                     float* __restrict__ out) {
    // 2048 float2 partials; 1024 threads, 2 each
    float2 a = ws[threadIdx.x];
    float2 b = ws[threadIdx.x + 1024];
    float d0 = a.x + b.x;
    float d1 = a.y + b.y;
    #pragma unroll
    for (int off = 32; off > 0; off >>= 1) {
        d0 += __shfl_down(d0, off, 64);
        d1 += __shfl_down(d1, off, 64);
    }
    __shared__ float s0[16], s1[16];
    const int lane = threadIdx.x & 63;
    const int wid  = threadIdx.x >> 6;
    if (lane == 0) { s0[wid] = d0; s1[wid] = d1; }
    __syncthreads();
    if (threadIdx.x == 0) {
        float t0 = 0.0f, t1 = 0.0f;
        #pragma unroll
        for (int k = 0; k < 16; ++k) { t0 += s0[k]; t1 += s1[k]; }
        const float inv_n = 1.0f / (float)N_ROWS;
        out[0] = t0 * inv_n;   // plain overwrite — no memset node needed
        out[1] = t1 * inv_n;
    }
}

extern "C" void kernel_launch(void* const* d_in, const int* in_sizes, int n_in,
                              void* d_out, int out_size, void* d_ws, size_t ws_size,
                              hipStream_t stream) {
    const float* inputs = (const float*)d_in[0];
    const int* targets = (const int*)d_in[1];
    float* out = (float*)d_out;
    float2* ws = (float2*)d_ws;   // needs 2048 * 8 = 16 KB scratch

    hinge_partials<<<GRID_BLKS, 256, 0, stream>>>((const float4*)inputs, inputs, targets, ws);
    hinge_reduce<<<1, 1024, 0, stream>>>(ws, out);
}